// Round 6
// baseline (459.541 us; speedup 1.0000x reference)
//
#include <hip/hip_runtime.h>
#include <math.h>

#define T_SEQ 2048
#define DMODEL 2048
#define DSTATE 128
#define NH 64
#define NG 8
#define HPG 8
#define HD 64
#define CH 256
#define NC 8
#define DIN 4096
#define CONVD 6144
#define DPROJ 10304
#define DPROJP 10368   // padded to 81*128; stored width of zx
#define BCW 2048       // width of bf16 B|C buffer (2*NG*DSTATE)
#define DTOFF 10240    // start of dt columns in zx
#define EPS 1e-5f

typedef short v8s __attribute__((ext_vector_type(8)));
typedef float v4f __attribute__((ext_vector_type(4)));

__device__ __forceinline__ float silu_f(float x) { return x / (1.0f + __expf(-x)); }

__device__ __forceinline__ unsigned short f2b(float x) {  // fp32 -> bf16 bits, RNE
    union { float f; unsigned u; } v; v.f = x;
    unsigned r = v.u + 0x7fffu + ((v.u >> 16) & 1u);
    return (unsigned short)(r >> 16);
}
__device__ __forceinline__ float b2f(unsigned short u) {
    union { unsigned u; float f; } v; v.u = ((unsigned)u) << 16; return v.f;
}

// ---------------- fused front converts: in_proj_w (with tail pad) + hidden, one launch
__global__ __launch_bounds__(256) void cvt_front(const float4* __restrict__ wsrc,
                                                 ushort4* __restrict__ wdst,
                                                 int n4s_w, int n4d_w,
                                                 const float4* __restrict__ hsrc,
                                                 ushort4* __restrict__ hdst, int n4_h) {
    int i = blockIdx.x * 256 + threadIdx.x;
    if (i < n4d_w) {
        ushort4 o = {0, 0, 0, 0};
        if (i < n4s_w) {
            float4 v = wsrc[i];
            o.x = f2b(v.x); o.y = f2b(v.y); o.z = f2b(v.z); o.w = f2b(v.w);
        }
        wdst[i] = o;
    } else {
        int j = i - n4d_w;
        if (j < n4_h) {
            float4 v = hsrc[j];
            ushort4 o = {f2b(v.x), f2b(v.y), f2b(v.z), f2b(v.w)};
            hdst[j] = o;
        }
    }
}

// ---------------- bf16 MFMA GEMM: C[M,N] = A[M,K] * B[N,K]^T   (128xBN, BK=32)
// m97-class kernel (the proven structure). 1-D grid, bijective XCD-chunked swizzle
// (m-fast): the mt blocks sharing a B-tile land on one XCD -> B-tile L2-resident
// (r5 measured: FETCH 174->90 MB, -4.4 us on in-proj).
// BN=128: in-proj (1296 blocks, 2/CU). BN=64: out-proj (512 blocks, 2/CU -> the
// barrier drain overlaps across blocks; fixes r2's 1-block/CU 10.6% occupancy).
template <int BN, bool OUTB>
__global__ __launch_bounds__(256) void gemm_bf16(const unsigned short* __restrict__ A,
                                                 const unsigned short* __restrict__ B,
                                                 float* __restrict__ Cf,
                                                 unsigned short* __restrict__ Cbo,
                                                 float* __restrict__ dtout,
                                                 int M, int N, int K, int nbase, int mt) {
    constexpr int BM = 128, BK = 32;
    constexpr int NWT = BN / 32;
    constexpr int BCH = (BN * BK * 2) / 1024;
    __shared__ short sA[BM * BK];
    __shared__ short sB[BN * BK];
    const int tid = threadIdx.x;
    const int wave = tid >> 6, lane = tid & 63;
    // bijective XCD swizzle (gridDim.x % 8 == 0), m-fast
    const int q = (int)gridDim.x >> 3;
    const int wg = ((int)blockIdx.x & 7) * q + ((int)blockIdx.x >> 3);
    const int m0 = (wg % mt) * BM, n0 = (wg / mt) * BN;
    const int wm = (wave >> 1) * 64;
    const int wn = (wave & 1) * (BN / 2);
    const int lr = lane & 15, kq = lane >> 4;

    v4f acc[4][NWT];
#pragma unroll
    for (int i = 0; i < 4; ++i)
#pragma unroll
        for (int j = 0; j < NWT; ++j) acc[i][j] = {0.f, 0.f, 0.f, 0.f};

    for (int k0 = 0; k0 < K; k0 += BK) {
#pragma unroll
        for (int qi = 0; qi < 2; ++qi) {
            int qq = wave * 2 + qi;
            int e = qq * 512 + lane * 8;
            int r = e >> 5, c = e & 31;
            __builtin_amdgcn_global_load_lds(
                (const __attribute__((address_space(1))) void*)(A + (size_t)(m0 + r) * K + k0 + c),
                (__attribute__((address_space(3))) void*)(sA + qq * 512), 16, 0, 0);
        }
        for (int qq = wave; qq < BCH; qq += 4) {
            int e = qq * 512 + lane * 8;
            int r = e >> 5, c = e & 31;
            __builtin_amdgcn_global_load_lds(
                (const __attribute__((address_space(1))) void*)(B + (size_t)(n0 + r) * K + k0 + c),
                (__attribute__((address_space(3))) void*)(sB + qq * 512), 16, 0, 0);
        }
        __syncthreads();
        v8s af[4], bf[NWT];
#pragma unroll
        for (int i = 0; i < 4; ++i)
            af[i] = *(const v8s*)(sA + (wm + i * 16 + lr) * BK + kq * 8);
#pragma unroll
        for (int j = 0; j < NWT; ++j)
            bf[j] = *(const v8s*)(sB + (wn + j * 16 + lr) * BK + kq * 8);
#pragma unroll
        for (int i = 0; i < 4; ++i)
#pragma unroll
            for (int j = 0; j < NWT; ++j)
                acc[i][j] = __builtin_amdgcn_mfma_f32_16x16x32_bf16(af[i], bf[j], acc[i][j], 0, 0, 0);
        __syncthreads();
    }
    const int crow = kq * 4, ccol = lr;
#pragma unroll
    for (int i = 0; i < 4; ++i)
#pragma unroll
        for (int j = 0; j < NWT; ++j) {
            const int col = nbase + n0 + wn + j * 16 + ccol;
            const int row0 = m0 + wm + i * 16 + crow;
#pragma unroll
            for (int r = 0; r < 4; ++r) {
                float v = acc[i][j][r];
                if (OUTB) {
                    Cbo[(size_t)(row0 + r) * N + col] = f2b(v);
                    if ((unsigned)(col - DTOFF) < 64u)
                        dtout[(size_t)(row0 + r) * 64 + (col - DTOFF)] = v;
                } else {
                    Cf[(size_t)(row0 + r) * N + col] = v;
                }
            }
        }
}

// ---------------- fused conv1d+SiLU (blocks 0..767) and dt/softplus/cumsum (768..1279)
__global__ __launch_bounds__(256) void convdt_kernel(const unsigned short* __restrict__ zxb,
                                                     const float* __restrict__ cw,
                                                     const float* __restrict__ cb,
                                                     unsigned short* __restrict__ Xt,
                                                     unsigned short* __restrict__ BCb,
                                                     unsigned short* __restrict__ Btr,
                                                     const float* __restrict__ dt_raw,
                                                     const float* __restrict__ A,
                                                     const float* __restrict__ dt_bias,
                                                     float* __restrict__ dt_s,
                                                     float* __restrict__ dAcs) {
    __shared__ unsigned short sh[64 * 262];    // [ch][t], stride 262 (odd dwords -> conflict-free)
    const int tid = threadIdx.x;
    if (blockIdx.x < NC * 96) {
        // ---- conv branch
        const int cc = blockIdx.x / 96, cg = blockIdx.x % 96;
        const int c0 = cg * 64;
        const int cl = tid & 63, tq = tid >> 6;    // channel lane, t-quarter (= wave id)
        const int ch = c0 + cl;
        const float4 w = ((const float4*)cw)[ch];
        const float bias = cb[ch];
        const int tg0 = cc * 256 + tq * 64;
        float x0 = (tg0 >= 3) ? b2f(zxb[(size_t)(tg0 - 3) * DPROJP + DIN + ch]) : 0.f;
        float x1 = (tg0 >= 2) ? b2f(zxb[(size_t)(tg0 - 2) * DPROJP + DIN + ch]) : 0.f;
        float x2 = (tg0 >= 1) ? b2f(zxb[(size_t)(tg0 - 1) * DPROJP + DIN + ch]) : 0.f;
#pragma unroll 8
        for (int i = 0; i < 64; ++i) {
            float x3 = b2f(zxb[(size_t)(tg0 + i) * DPROJP + DIN + ch]);
            float acc = bias + x0 * w.x + x1 * w.y + x2 * w.z + x3 * w.w;
            sh[cl * 262 + tq * 64 + i] = f2b(silu_f(acc));
            x0 = x1; x1 = x2; x2 = x3;
        }
        __syncthreads();
        if (c0 < DIN) {
            const int h = c0 >> 6;
            unsigned short* dst = Xt + (size_t)(cc * NH + h) * HD * CH;
#pragma unroll
            for (int it = 0; it < 8; ++it) {
                int flat = it * 256 + tid;
                int row = flat >> 5, col = (flat & 31) * 8;
                *(ushort4*)&dst[(size_t)row * CH + col]     = *(ushort4*)&sh[row * 262 + col];
                *(ushort4*)&dst[(size_t)row * CH + col + 4] = *(ushort4*)&sh[row * 262 + col + 4];
            }
        } else {
            const int bc0 = c0 - DIN;
            for (int it = 0; it < 64; ++it) {
                int t = it * 4 + tq;
                BCb[(size_t)(cc * 256 + t) * BCW + bc0 + cl] = sh[cl * 262 + t];
            }
            if (bc0 < NG * DSTATE) {
                unsigned short* dst = Btr + ((size_t)cc * (NG * DSTATE) + bc0) * CH;
#pragma unroll
                for (int it = 0; it < 8; ++it) {
                    int flat = it * 256 + tid;
                    int row = flat >> 5, col = (flat & 31) * 8;
                    *(ushort4*)&dst[(size_t)row * CH + col]     = *(ushort4*)&sh[row * 262 + col];
                    *(ushort4*)&dst[(size_t)row * CH + col + 4] = *(ushort4*)&sh[row * 262 + col + 4];
                }
            }
        }
    } else {
        // ---- dt branch: softplus + within-chunk cumsum of dt*A
        float* s = (float*)sh;                  // 1 KB alias
        const int bid = blockIdx.x - NC * 96;
        int h = bid % NH, c = bid / NH;
        int t = tid;
        int tg = c * CH + t;
        float raw = dt_raw[(size_t)tg * 64 + h] + dt_bias[h];
        float dtv = (raw > 20.0f) ? raw : log1pf(__expf(raw));
        s[t] = dtv * A[h];
        __syncthreads();
        for (int off = 1; off < CH; off <<= 1) {
            float add = (t >= off) ? s[t - off] : 0.0f;
            __syncthreads();
            s[t] += add;
            __syncthreads();
        }
        dt_s[h * T_SEQ + tg] = dtv;
        dAcs[h * T_SEQ + tg] = s[t];
    }
}

// ---------------- MFMA states: states[c,h,p,n] = sum_t Xt[p,t] * (w2[t]*Btr[n,t])
__global__ __launch_bounds__(256) void states_mfma(const unsigned short* __restrict__ Xt,
                                                   const unsigned short* __restrict__ Btr,
                                                   const float* __restrict__ dt_s,
                                                   const float* __restrict__ dAcs,
                                                   float* __restrict__ states) {
    __shared__ float w2sh[CH];
    const int h = blockIdx.x % NH, c = blockIdx.x / NH, g = h >> 3;
    const int tid = threadIdx.x, wave = tid >> 6, lane = tid & 63;
    const int lr = lane & 15, quad = lane >> 4;
    float da_last = dAcs[h * T_SEQ + c * CH + CH - 1];
    w2sh[tid] = __expf(da_last - dAcs[h * T_SEQ + c * CH + tid]) * dt_s[h * T_SEQ + c * CH + tid];
    __syncthreads();
    const unsigned short* Xr = Xt + (size_t)(c * NH + h) * HD * CH;
    const unsigned short* Br = Btr + (size_t)(c * NG + g) * DSTATE * CH;

    v4f acc[4][2];
#pragma unroll
    for (int i = 0; i < 4; ++i)
#pragma unroll
        for (int j = 0; j < 2; ++j) acc[i][j] = {0.f, 0.f, 0.f, 0.f};

    for (int kb = 0; kb < 8; ++kb) {
        const int t0 = kb * 32 + quad * 8;
        float w[8];
        {
            float4 wa = *(const float4*)&w2sh[t0];
            float4 wb = *(const float4*)&w2sh[t0 + 4];
            w[0] = wa.x; w[1] = wa.y; w[2] = wa.z; w[3] = wa.w;
            w[4] = wb.x; w[5] = wb.y; w[6] = wb.z; w[7] = wb.w;
        }
        v8s bf[2];
#pragma unroll
        for (int j = 0; j < 2; ++j) {
            v8s raw = *(const v8s*)(Br + (size_t)(wave * 32 + j * 16 + lr) * CH + t0);
            v8s o;
#pragma unroll
            for (int e = 0; e < 8; ++e) o[e] = (short)f2b(b2f((unsigned short)raw[e]) * w[e]);
            bf[j] = o;
        }
        v8s af[4];
#pragma unroll
        for (int i = 0; i < 4; ++i)
            af[i] = *(const v8s*)(Xr + (size_t)(i * 16 + lr) * CH + t0);
#pragma unroll
        for (int i = 0; i < 4; ++i)
#pragma unroll
            for (int j = 0; j < 2; ++j)
                acc[i][j] = __builtin_amdgcn_mfma_f32_16x16x32_bf16(af[i], bf[j], acc[i][j], 0, 0, 0);
    }
#pragma unroll
    for (int i = 0; i < 4; ++i)
#pragma unroll
        for (int j = 0; j < 2; ++j)
#pragma unroll
            for (int r = 0; r < 4; ++r)
                states[((size_t)(c * NH + h) * HD + i * 16 + quad * 4 + r) * DSTATE +
                       wave * 32 + j * 16 + lr] = acc[i][j][r];
}

// ---------------- sequential chunk scan, 512 blocks: prev_b[c] (bf16) = carry before chunk c
__global__ __launch_bounds__(256) void scan_kernel(const float* __restrict__ states,
                                                   const float* __restrict__ dAcs,
                                                   unsigned short* __restrict__ prev_b) {
    int h = blockIdx.x >> 3, seg = blockIdx.x & 7;
    int base = seg * 1024 + threadIdx.x * 4;
    float4 carry = {0.f, 0.f, 0.f, 0.f};
    for (int c = 0; c < NC; ++c) {
        size_t off = (size_t)(c * NH + h) * (HD * DSTATE) + base;
        ushort4 o = {f2b(carry.x), f2b(carry.y), f2b(carry.z), f2b(carry.w)};
        *(ushort4*)&prev_b[off] = o;
        float cd = __expf(dAcs[h * T_SEQ + c * CH + CH - 1]);
        float4 s = *(const float4*)&states[off];
        carry.x = fmaf(carry.x, cd, s.x);
        carry.y = fmaf(carry.y, cd, s.y);
        carry.z = fmaf(carry.z, cd, s.z);
        carry.w = fmaf(carry.w, cd, s.w);
    }
}

// ---------------- fused intra + inter chunk output, one block per (c,h)
__global__ __launch_bounds__(256) void y12_mfma(const unsigned short* __restrict__ BCb,
                                                const unsigned short* __restrict__ Xt,
                                                const unsigned short* __restrict__ prev_b,
                                                const float* __restrict__ dt_s,
                                                const float* __restrict__ dAcs,
                                                const float* __restrict__ Dp,
                                                float* __restrict__ yacc) {
    __shared__ float s_da[CH], s_dt[CH];
    __shared__ unsigned short pw[4][16][40];
    const int h = blockIdx.x % NH, c = blockIdx.x / NH, g = h >> 3;
    const int tid = threadIdx.x, wave = tid >> 6, lane = tid & 63;
    const int lr = lane & 15, quad = lane >> 4;
    s_da[tid] = dAcs[h * T_SEQ + c * CH + tid];
    s_dt[tid] = dt_s[h * T_SEQ + c * CH + tid];
    __syncthreads();

    const unsigned short* Cb = BCb + (size_t)c * CH * BCW + NG * DSTATE + g * DSTATE;
    const unsigned short* Bb = BCb + (size_t)c * CH * BCW + g * DSTATE;
    const unsigned short* Xr = Xt + (size_t)(c * NH + h) * HD * CH;
    const unsigned short* Pr = prev_b + (size_t)(c * NH + h) * HD * DSTATE;
    const float Dh = Dp[h];

    v4f Y[4][4];  // [st_local][pj], st = i*4 + wave
#pragma unroll
    for (int i = 0; i < 4; ++i)
#pragma unroll
        for (int j = 0; j < 4; ++j) Y[i][j] = {0.f, 0.f, 0.f, 0.f};

    // ---- inter-chunk: Y = Cb · prev^T (raw), then scale output rows by e^{dA_s}
    //      (e^{da_s} multiplies C rows == MFMA output rows: 64-mul epilogue instead
    //       of a 128-element bf16 A-fragment repack; r5-verified, absmax unchanged)
#pragma unroll
    for (int kb = 0; kb < 4; ++kb) {
        const int n0 = kb * 32 + quad * 8;
        v8s bfp[4];
#pragma unroll
        for (int pj = 0; pj < 4; ++pj)
            bfp[pj] = *(const v8s*)(Pr + (size_t)(pj * 16 + lr) * DSTATE + n0);
#pragma unroll
        for (int i = 0; i < 4; ++i) {
            int st = i * 4 + wave;
            v8s af = *(const v8s*)(Cb + (size_t)(st * 16 + lr) * BCW + n0);
#pragma unroll
            for (int pj = 0; pj < 4; ++pj)
                Y[i][pj] = __builtin_amdgcn_mfma_f32_16x16x32_bf16(af, bfp[pj], Y[i][pj], 0, 0, 0);
        }
    }
#pragma unroll
    for (int i = 0; i < 4; ++i) {
        int st = i * 4 + wave;
#pragma unroll
        for (int r = 0; r < 4; ++r) {
            float es = __expf(s_da[st * 16 + quad * 4 + r]);
#pragma unroll
            for (int pj = 0; pj < 4; ++pj) Y[i][pj][r] *= es;
        }
    }

    // ---- intra-chunk (causal tiles only)
    for (int tb = 0; tb < 8; ++tb) {
        if (12 + wave < 2 * tb) continue;
        const int t0q = tb * 32 + quad * 8;
        v8s xf[4];
#pragma unroll
        for (int pj = 0; pj < 4; ++pj)
            xf[pj] = *(const v8s*)(Xr + (size_t)(pj * 16 + lr) * CH + t0q);
        v8s bfr[2][4];
#pragma unroll
        for (int j = 0; j < 2; ++j)
#pragma unroll
            for (int ks = 0; ks < 4; ++ks)
                bfr[j][ks] = *(const v8s*)(Bb + (size_t)(tb * 32 + j * 16 + lr) * BCW + ks * 32 + quad * 8);
#pragma unroll
        for (int i = 0; i < 4; ++i) {
            int st = i * 4 + wave;
            if (st < 2 * tb) continue;
            v4f S0 = {0.f, 0.f, 0.f, 0.f}, S1 = {0.f, 0.f, 0.f, 0.f};
#pragma unroll
            for (int ks = 0; ks < 4; ++ks) {
                v8s af = *(const v8s*)(Cb + (size_t)(st * 16 + lr) * BCW + ks * 32 + quad * 8);
                S0 = __builtin_amdgcn_mfma_f32_16x16x32_bf16(af, bfr[0][ks], S0, 0, 0, 0);
                S1 = __builtin_amdgcn_mfma_f32_16x16x32_bf16(af, bfr[1][ks], S1, 0, 0, 0);
            }
            int t0 = tb * 32 + lr;
            float da0 = s_da[t0], dt0 = s_dt[t0];
            float da1 = s_da[t0 + 16], dt1 = s_dt[t0 + 16];
#pragma unroll
            for (int r = 0; r < 4; ++r) {
                int s = st * 16 + quad * 4 + r;
                float das = s_da[s];
                float w0 = (t0 <= s) ? S0[r] * __expf(das - da0) * dt0 : 0.f;
                float w1 = (t0 + 16 <= s) ? S1[r] * __expf(das - da1) * dt1 : 0.f;
                if (t0 == s) w0 += Dh;            // D folded into diagonal
                if (t0 + 16 == s) w1 += Dh;
                pw[wave][quad * 4 + r][lr] = f2b(w0);
                pw[wave][quad * 4 + r][16 + lr] = f2b(w1);
            }
            v8s pf = *(const v8s*)(&pw[wave][lr][quad * 8]);  // same-wave LDS round-trip
#pragma unroll
            for (int pj = 0; pj < 4; ++pj)
                Y[i][pj] = __builtin_amdgcn_mfma_f32_16x16x32_bf16(pf, xf[pj], Y[i][pj], 0, 0, 0);
        }
    }
    // epilogue: single write
#pragma unroll
    for (int i = 0; i < 4; ++i) {
        int st = i * 4 + wave;
#pragma unroll
        for (int pj = 0; pj < 4; ++pj) {
            int p = pj * 16 + lr;
#pragma unroll
            for (int r = 0; r < 4; ++r) {
                int s = st * 16 + quad * 4 + r;
                yacc[(size_t)(c * CH + s) * DIN + h * HD + p] = Y[i][pj][r];
            }
        }
    }
}

// ---------------- fused: grouped RMSNorm+gate (blocks 0..8191, 2 groups/block)
//                  and out_proj_w fp32->bf16 convert (blocks 8192..16383)
__global__ __launch_bounds__(256) void normcvt_kernel(const unsigned short* __restrict__ zxb,
                                                      const float* __restrict__ yacc,
                                                      const float* __restrict__ norm_w,
                                                      unsigned short* __restrict__ ynorm,
                                                      const float4* __restrict__ osrc,
                                                      ushort4* __restrict__ odst) {
    if (blockIdx.x < 8192) {
        __shared__ float red[4];
        const int sub = threadIdx.x >> 7, tid = threadIdx.x & 127;
        const int gid = blockIdx.x * 2 + sub;
        const int t = gid / NG, g = gid % NG;
        const int j = g * 512 + tid * 4;
        float4 y4 = *(const float4*)&yacc[(size_t)t * DIN + j];
        ushort4 z4 = *(const ushort4*)&zxb[(size_t)t * DPROJP + j];
        float v0 = y4.x * silu_f(b2f(z4.x));
        float v1 = y4.y * silu_f(b2f(z4.y));
        float v2 = y4.z * silu_f(b2f(z4.z));
        float v3 = y4.w * silu_f(b2f(z4.w));
        float ss = v0 * v0 + v1 * v1 + v2 * v2 + v3 * v3;
#pragma unroll
        for (int off = 32; off > 0; off >>= 1) ss += __shfl_down(ss, off, 64);
        if ((threadIdx.x & 63) == 0) red[threadIdx.x >> 6] = ss;
        __syncthreads();
        float var = (red[sub * 2] + red[sub * 2 + 1]) * (1.0f / 512.0f);
        float scale = rsqrtf(var + EPS);
        float4 w4 = *(const float4*)&norm_w[j];
        ushort4 o = {f2b(v0 * scale * w4.x), f2b(v1 * scale * w4.y),
                     f2b(v2 * scale * w4.z), f2b(v3 * scale * w4.w)};
        *(ushort4*)&ynorm[(size_t)t * DIN + j] = o;
    } else {
        int i = (blockIdx.x - 8192) * 256 + threadIdx.x;   // i < DMODEL*DIN/4 = 2,097,152
        float4 v = osrc[i];
        ushort4 o = {f2b(v.x), f2b(v.y), f2b(v.z), f2b(v.w)};
        odst[i] = o;
    }
}

extern "C" void kernel_launch(void* const* d_in, const int* in_sizes, int n_in,
                              void* d_out, int out_size, void* d_ws, size_t ws_size,
                              hipStream_t stream) {
    const float* hidden     = (const float*)d_in[0];
    const float* in_proj_w  = (const float*)d_in[1];
    const float* conv_w     = (const float*)d_in[2];
    const float* conv_b     = (const float*)d_in[3];
    const float* A          = (const float*)d_in[4];
    const float* Dp         = (const float*)d_in[5];
    const float* dt_bias    = (const float*)d_in[6];
    const float* norm_w     = (const float*)d_in[7];
    const float* out_proj_w = (const float*)d_in[8];
    float* out = (float*)d_out;

    // workspace layout (fp32 words) — total 34,209,792 words = 136.8 MB
    float* ws     = (float*)d_ws;
    unsigned short* zxb = (unsigned short*)ws;          // bf16 [T, DPROJP]: 10,616,832 w
    float* dt_raw = ws + 10616832;                      //                     131,072 w
    float* dt_s   = dt_raw + 131072;                    //                     131,072 w
    float* dAcs   = dt_s + 131072;                      //                     131,072 w
    float* yacc   = dAcs + 131072;                      // fp32 [T, DIN]:    8,388,608 w
    float* regE   = yacc + 8388608;                     //                  10,616,832 w
    float* regF   = regE + 10616832;                    //                   4,194,304 w

    // regE phases: inw_b (gemm1, 42.5MB) -> Xt [0,4.19M w) + states [4.19M,8.39M w)
    //              -> outw_b [0,4.19M w) after y12
    unsigned short* inw_b  = (unsigned short*)regE;
    unsigned short* Xt_b   = (unsigned short*)regE;                 // conv -> y12
    float*          states = regE + 4194304;                        // states_mfma -> scan
    unsigned short* outw_b = (unsigned short*)regE;                 // cvt -> out-proj
    // regF phases: hidden_b (gemm1) -> BCb [0,2.1M w) + Btr [2.1M,3.15M w)
    //              -> prev_b [2.1M,4.19M w) over Btr after states -> ynorm_b [0,4.19M w) after y12
    unsigned short* hidden_b = (unsigned short*)regF;
    unsigned short* BCb      = (unsigned short*)regF;
    unsigned short* Btr      = (unsigned short*)(regF + 2097152);
    unsigned short* prev_b   = (unsigned short*)(regF + 2097152);
    unsigned short* ynorm_b  = (unsigned short*)regF;

    // --- fused front converts (in_proj_w + hidden)
    {
        int n4s = DPROJ * DMODEL / 4, n4d = DPROJP * DMODEL / 4;
        int h4 = T_SEQ * DMODEL / 4;
        cvt_front<<<(n4d + h4 + 255) / 256, 256, 0, stream>>>(
            (const float4*)in_proj_w, (ushort4*)inw_b, n4s, n4d,
            (const float4*)hidden, (ushort4*)hidden_b, h4);
    }
    // --- in-proj GEMM: 1-D grid 1296 (16 m x 81 n), XCD-chunked swizzle m-fast
    gemm_bf16<128, true><<<dim3(16 * 81), 256, 0, stream>>>(
        hidden_b, inw_b, nullptr, zxb, dt_raw, T_SEQ, DPROJP, DMODEL, 0, 16);

    // --- fused conv + dt (1280 blocks)
    convdt_kernel<<<NC * 96 + NC * NH, 256, 0, stream>>>(
        zxb, conv_w, conv_b, Xt_b, BCb, Btr, dt_raw, A, dt_bias, dt_s, dAcs);

    states_mfma<<<NC * NH, 256, 0, stream>>>(Xt_b, Btr, dt_s, dAcs, states);
    scan_kernel<<<NH * 8, 256, 0, stream>>>(states, dAcs, prev_b);
    y12_mfma<<<NC * NH, 256, 0, stream>>>(BCb, Xt_b, prev_b, dt_s, dAcs, Dp, yacc);

    // --- fused norm (2 groups/block) + out_proj_w convert (Xt + states dead now)
    normcvt_kernel<<<16384, 256, 0, stream>>>(
        zxb, yacc, norm_w, ynorm_b, (const float4*)out_proj_w, (ushort4*)outw_b);

    // --- out-proj GEMM: BN=64/BK=32 (proven staging structure, 2 blocks/CU)
    //     1-D grid 512 (16 m x 32 n), XCD-chunked swizzle m-fast
    gemm_bf16<64, false><<<dim3(16 * 32), 256, 0, stream>>>(
        ynorm_b, outw_b, out, nullptr, nullptr, T_SEQ, DMODEL, DIN, 0, 16);
}

// Round 7
// 446.810 us; speedup vs baseline: 1.0285x; 1.0285x over previous
//
#include <hip/hip_runtime.h>
#include <math.h>

#define T_SEQ 2048
#define DMODEL 2048
#define DSTATE 128
#define NH 64
#define NG 8
#define HPG 8
#define HD 64
#define CH 256
#define NC 8
#define DIN 4096
#define CONVD 6144
#define DPROJ 10304
#define DPROJP 10368   // padded to 81*128; stored width of zx
#define BCW 2048       // width of bf16 B|C buffer (2*NG*DSTATE)
#define DTOFF 10240    // start of dt columns in zx
#define EPS 1e-5f

typedef short v8s __attribute__((ext_vector_type(8)));
typedef float v4f __attribute__((ext_vector_type(4)));

__device__ __forceinline__ float silu_f(float x) { return x / (1.0f + __expf(-x)); }

__device__ __forceinline__ unsigned short f2b(float x) {  // fp32 -> bf16 bits, RNE
    union { float f; unsigned u; } v; v.f = x;
    unsigned r = v.u + 0x7fffu + ((v.u >> 16) & 1u);
    return (unsigned short)(r >> 16);
}
__device__ __forceinline__ float b2f(unsigned short u) {
    union { unsigned u; float f; } v; v.u = ((unsigned)u) << 16; return v.f;
}

// ---------------- fused front converts: in_proj_w (with tail pad) + hidden, one launch
__global__ __launch_bounds__(256) void cvt_front(const float4* __restrict__ wsrc,
                                                 ushort4* __restrict__ wdst,
                                                 int n4s_w, int n4d_w,
                                                 const float4* __restrict__ hsrc,
                                                 ushort4* __restrict__ hdst, int n4_h) {
    int i = blockIdx.x * 256 + threadIdx.x;
    if (i < n4d_w) {
        ushort4 o = {0, 0, 0, 0};
        if (i < n4s_w) {
            float4 v = wsrc[i];
            o.x = f2b(v.x); o.y = f2b(v.y); o.z = f2b(v.z); o.w = f2b(v.w);
        }
        wdst[i] = o;
    } else {
        int j = i - n4d_w;
        if (j < n4_h) {
            float4 v = hsrc[j];
            ushort4 o = {f2b(v.x), f2b(v.y), f2b(v.z), f2b(v.w)};
            hdst[j] = o;
        }
    }
}

// ---------------- bf16 MFMA GEMM: C[M,N] = A[M,K] * B[N,K]^T   (128x128, BK=32)
// m97-class kernel, in-proj only. 1-D grid, bijective XCD-chunked swizzle (m-fast):
// the 16 blocks sharing a B-tile land on one XCD -> B-tile L2-resident.
// Isolated dispatch A/B (r4<->r5/r6): 130.0 -> 126.4 us, FETCH 174 -> 90 MB.
template <int BN, bool OUTB>
__global__ __launch_bounds__(256) void gemm_bf16(const unsigned short* __restrict__ A,
                                                 const unsigned short* __restrict__ B,
                                                 float* __restrict__ Cf,
                                                 unsigned short* __restrict__ Cbo,
                                                 float* __restrict__ dtout,
                                                 int M, int N, int K, int nbase, int mt) {
    constexpr int BM = 128, BK = 32;
    constexpr int NWT = BN / 32;
    constexpr int BCH = (BN * BK * 2) / 1024;
    __shared__ short sA[BM * BK];
    __shared__ short sB[BN * BK];
    const int tid = threadIdx.x;
    const int wave = tid >> 6, lane = tid & 63;
    // bijective XCD swizzle (gridDim.x % 8 == 0), m-fast
    const int q = (int)gridDim.x >> 3;
    const int wg = ((int)blockIdx.x & 7) * q + ((int)blockIdx.x >> 3);
    const int m0 = (wg % mt) * BM, n0 = (wg / mt) * BN;
    const int wm = (wave >> 1) * 64;
    const int wn = (wave & 1) * (BN / 2);
    const int lr = lane & 15, kq = lane >> 4;

    v4f acc[4][NWT];
#pragma unroll
    for (int i = 0; i < 4; ++i)
#pragma unroll
        for (int j = 0; j < NWT; ++j) acc[i][j] = {0.f, 0.f, 0.f, 0.f};

    for (int k0 = 0; k0 < K; k0 += BK) {
#pragma unroll
        for (int qi = 0; qi < 2; ++qi) {
            int qq = wave * 2 + qi;
            int e = qq * 512 + lane * 8;
            int r = e >> 5, c = e & 31;
            __builtin_amdgcn_global_load_lds(
                (const __attribute__((address_space(1))) void*)(A + (size_t)(m0 + r) * K + k0 + c),
                (__attribute__((address_space(3))) void*)(sA + qq * 512), 16, 0, 0);
        }
        for (int qq = wave; qq < BCH; qq += 4) {
            int e = qq * 512 + lane * 8;
            int r = e >> 5, c = e & 31;
            __builtin_amdgcn_global_load_lds(
                (const __attribute__((address_space(1))) void*)(B + (size_t)(n0 + r) * K + k0 + c),
                (__attribute__((address_space(3))) void*)(sB + qq * 512), 16, 0, 0);
        }
        __syncthreads();
        v8s af[4], bf[NWT];
#pragma unroll
        for (int i = 0; i < 4; ++i)
            af[i] = *(const v8s*)(sA + (wm + i * 16 + lr) * BK + kq * 8);
#pragma unroll
        for (int j = 0; j < NWT; ++j)
            bf[j] = *(const v8s*)(sB + (wn + j * 16 + lr) * BK + kq * 8);
#pragma unroll
        for (int i = 0; i < 4; ++i)
#pragma unroll
            for (int j = 0; j < NWT; ++j)
                acc[i][j] = __builtin_amdgcn_mfma_f32_16x16x32_bf16(af[i], bf[j], acc[i][j], 0, 0, 0);
        __syncthreads();
    }
    const int crow = kq * 4, ccol = lr;
#pragma unroll
    for (int i = 0; i < 4; ++i)
#pragma unroll
        for (int j = 0; j < NWT; ++j) {
            const int col = nbase + n0 + wn + j * 16 + ccol;
            const int row0 = m0 + wm + i * 16 + crow;
#pragma unroll
            for (int r = 0; r < 4; ++r) {
                float v = acc[i][j][r];
                if (OUTB) {
                    Cbo[(size_t)(row0 + r) * N + col] = f2b(v);
                    if ((unsigned)(col - DTOFF) < 64u)
                        dtout[(size_t)(row0 + r) * 64 + (col - DTOFF)] = v;
                } else {
                    Cf[(size_t)(row0 + r) * N + col] = v;
                }
            }
        }
}

// ---------------- bf16 MFMA GEMM: BK=64 + both-sides XOR swizzle (conflict-free).
// Out-proj only, BN=64: 2-D grid (16,32) = 512 blocks = 2/CU. This is R4's exact
// config (best measured total); R2->R3 accounting gives ~59 us for this dispatch.
template <int BN, bool OUTB>
__global__ __launch_bounds__(256) void gemm64_bf16(const unsigned short* __restrict__ A,
                                                   const unsigned short* __restrict__ B,
                                                   float* __restrict__ Cf,
                                                   unsigned short* __restrict__ Cbo,
                                                   float* __restrict__ dtout,
                                                   int M, int N, int K, int nbase) {
    constexpr int BM = 128, BK = 64;
    constexpr int NWT = BN / 32;
    constexpr int BSEGW = BN / 32;
    __shared__ short sA[BM * BK];
    __shared__ short sB[BN * BK];
    const int tid = threadIdx.x;
    const int wave = tid >> 6, lane = tid & 63;
    const int m0 = blockIdx.x * BM, n0 = blockIdx.y * BN;
    const int wm = (wave >> 1) * 64;
    const int wn = (wave & 1) * (BN / 2);
    const int lr = lane & 15, kq = lane >> 4;

    const int r8 = lane >> 3, c8 = lane & 7;
    const int gq = (c8 ^ r8) * 8;
    const int ck0 = ((kq) ^ (lr & 7)) * 8;
    const int ck1 = ((kq + 4) ^ (lr & 7)) * 8;

    v4f acc[4][NWT];
#pragma unroll
    for (int i = 0; i < 4; ++i)
#pragma unroll
        for (int j = 0; j < NWT; ++j) acc[i][j] = {0.f, 0.f, 0.f, 0.f};

    for (int k0 = 0; k0 < K; k0 += BK) {
#pragma unroll
        for (int s = 0; s < 4; ++s) {
            const int seg = wave * 4 + s;
            const int r = seg * 8 + r8;
            __builtin_amdgcn_global_load_lds(
                (const __attribute__((address_space(1))) void*)(A + (size_t)(m0 + r) * K + k0 + gq),
                (__attribute__((address_space(3))) void*)(sA + seg * 512 + lane * 8), 16, 0, 0);
        }
#pragma unroll
        for (int s = 0; s < BSEGW; ++s) {
            const int seg = wave * BSEGW + s;
            const int r = seg * 8 + r8;
            __builtin_amdgcn_global_load_lds(
                (const __attribute__((address_space(1))) void*)(B + (size_t)(n0 + r) * K + k0 + gq),
                (__attribute__((address_space(3))) void*)(sB + seg * 512 + lane * 8), 16, 0, 0);
        }
        __syncthreads();
#pragma unroll
        for (int kk = 0; kk < 2; ++kk) {
            const int ck = kk ? ck1 : ck0;
            v8s af[4], bf[NWT];
#pragma unroll
            for (int i = 0; i < 4; ++i)
                af[i] = *(const v8s*)(sA + (wm + i * 16 + lr) * BK + ck);
#pragma unroll
            for (int j = 0; j < NWT; ++j)
                bf[j] = *(const v8s*)(sB + (wn + j * 16 + lr) * BK + ck);
#pragma unroll
            for (int i = 0; i < 4; ++i)
#pragma unroll
                for (int j = 0; j < NWT; ++j)
                    acc[i][j] = __builtin_amdgcn_mfma_f32_16x16x32_bf16(af[i], bf[j], acc[i][j], 0, 0, 0);
        }
        __syncthreads();
    }
    const int crow = kq * 4, ccol = lr;
#pragma unroll
    for (int i = 0; i < 4; ++i)
#pragma unroll
        for (int j = 0; j < NWT; ++j) {
            const int col = nbase + n0 + wn + j * 16 + ccol;
            const int row0 = m0 + wm + i * 16 + crow;
#pragma unroll
            for (int r = 0; r < 4; ++r) {
                float v = acc[i][j][r];
                if (OUTB) {
                    Cbo[(size_t)(row0 + r) * N + col] = f2b(v);
                    if ((unsigned)(col - DTOFF) < 64u)
                        dtout[(size_t)(row0 + r) * 64 + (col - DTOFF)] = v;
                } else {
                    Cf[(size_t)(row0 + r) * N + col] = v;
                }
            }
        }
}

// ---------------- fused conv1d+SiLU (blocks 0..767) and dt/softplus/cumsum (768..1279)
__global__ __launch_bounds__(256) void convdt_kernel(const unsigned short* __restrict__ zxb,
                                                     const float* __restrict__ cw,
                                                     const float* __restrict__ cb,
                                                     unsigned short* __restrict__ Xt,
                                                     unsigned short* __restrict__ BCb,
                                                     unsigned short* __restrict__ Btr,
                                                     const float* __restrict__ dt_raw,
                                                     const float* __restrict__ A,
                                                     const float* __restrict__ dt_bias,
                                                     float* __restrict__ dt_s,
                                                     float* __restrict__ dAcs) {
    __shared__ unsigned short sh[64 * 262];    // [ch][t], stride 262 (odd dwords -> conflict-free)
    const int tid = threadIdx.x;
    if (blockIdx.x < NC * 96) {
        // ---- conv branch
        const int cc = blockIdx.x / 96, cg = blockIdx.x % 96;
        const int c0 = cg * 64;
        const int cl = tid & 63, tq = tid >> 6;    // channel lane, t-quarter (= wave id)
        const int ch = c0 + cl;
        const float4 w = ((const float4*)cw)[ch];
        const float bias = cb[ch];
        const int tg0 = cc * 256 + tq * 64;
        float x0 = (tg0 >= 3) ? b2f(zxb[(size_t)(tg0 - 3) * DPROJP + DIN + ch]) : 0.f;
        float x1 = (tg0 >= 2) ? b2f(zxb[(size_t)(tg0 - 2) * DPROJP + DIN + ch]) : 0.f;
        float x2 = (tg0 >= 1) ? b2f(zxb[(size_t)(tg0 - 1) * DPROJP + DIN + ch]) : 0.f;
#pragma unroll 8
        for (int i = 0; i < 64; ++i) {
            float x3 = b2f(zxb[(size_t)(tg0 + i) * DPROJP + DIN + ch]);
            float acc = bias + x0 * w.x + x1 * w.y + x2 * w.z + x3 * w.w;
            sh[cl * 262 + tq * 64 + i] = f2b(silu_f(acc));
            x0 = x1; x1 = x2; x2 = x3;
        }
        __syncthreads();
        if (c0 < DIN) {
            const int h = c0 >> 6;
            unsigned short* dst = Xt + (size_t)(cc * NH + h) * HD * CH;
#pragma unroll
            for (int it = 0; it < 8; ++it) {
                int flat = it * 256 + tid;
                int row = flat >> 5, col = (flat & 31) * 8;
                *(ushort4*)&dst[(size_t)row * CH + col]     = *(ushort4*)&sh[row * 262 + col];
                *(ushort4*)&dst[(size_t)row * CH + col + 4] = *(ushort4*)&sh[row * 262 + col + 4];
            }
        } else {
            const int bc0 = c0 - DIN;
            for (int it = 0; it < 64; ++it) {
                int t = it * 4 + tq;
                BCb[(size_t)(cc * 256 + t) * BCW + bc0 + cl] = sh[cl * 262 + t];
            }
            if (bc0 < NG * DSTATE) {
                unsigned short* dst = Btr + ((size_t)cc * (NG * DSTATE) + bc0) * CH;
#pragma unroll
                for (int it = 0; it < 8; ++it) {
                    int flat = it * 256 + tid;
                    int row = flat >> 5, col = (flat & 31) * 8;
                    *(ushort4*)&dst[(size_t)row * CH + col]     = *(ushort4*)&sh[row * 262 + col];
                    *(ushort4*)&dst[(size_t)row * CH + col + 4] = *(ushort4*)&sh[row * 262 + col + 4];
                }
            }
        }
    } else {
        // ---- dt branch: softplus + within-chunk cumsum of dt*A
        float* s = (float*)sh;                  // 1 KB alias
        const int bid = blockIdx.x - NC * 96;
        int h = bid % NH, c = bid / NH;
        int t = tid;
        int tg = c * CH + t;
        float raw = dt_raw[(size_t)tg * 64 + h] + dt_bias[h];
        float dtv = (raw > 20.0f) ? raw : log1pf(__expf(raw));
        s[t] = dtv * A[h];
        __syncthreads();
        for (int off = 1; off < CH; off <<= 1) {
            float add = (t >= off) ? s[t - off] : 0.0f;
            __syncthreads();
            s[t] += add;
            __syncthreads();
        }
        dt_s[h * T_SEQ + tg] = dtv;
        dAcs[h * T_SEQ + tg] = s[t];
    }
}

// ---------------- MFMA states: states[c,h,p,n] = sum_t Xt[p,t] * (w2[t]*Btr[n,t])
__global__ __launch_bounds__(256) void states_mfma(const unsigned short* __restrict__ Xt,
                                                   const unsigned short* __restrict__ Btr,
                                                   const float* __restrict__ dt_s,
                                                   const float* __restrict__ dAcs,
                                                   float* __restrict__ states) {
    __shared__ float w2sh[CH];
    const int h = blockIdx.x % NH, c = blockIdx.x / NH, g = h >> 3;
    const int tid = threadIdx.x, wave = tid >> 6, lane = tid & 63;
    const int lr = lane & 15, quad = lane >> 4;
    float da_last = dAcs[h * T_SEQ + c * CH + CH - 1];
    w2sh[tid] = __expf(da_last - dAcs[h * T_SEQ + c * CH + tid]) * dt_s[h * T_SEQ + c * CH + tid];
    __syncthreads();
    const unsigned short* Xr = Xt + (size_t)(c * NH + h) * HD * CH;
    const unsigned short* Br = Btr + (size_t)(c * NG + g) * DSTATE * CH;

    v4f acc[4][2];
#pragma unroll
    for (int i = 0; i < 4; ++i)
#pragma unroll
        for (int j = 0; j < 2; ++j) acc[i][j] = {0.f, 0.f, 0.f, 0.f};

    for (int kb = 0; kb < 8; ++kb) {
        const int t0 = kb * 32 + quad * 8;
        float w[8];
        {
            float4 wa = *(const float4*)&w2sh[t0];
            float4 wb = *(const float4*)&w2sh[t0 + 4];
            w[0] = wa.x; w[1] = wa.y; w[2] = wa.z; w[3] = wa.w;
            w[4] = wb.x; w[5] = wb.y; w[6] = wb.z; w[7] = wb.w;
        }
        v8s bf[2];
#pragma unroll
        for (int j = 0; j < 2; ++j) {
            v8s raw = *(const v8s*)(Br + (size_t)(wave * 32 + j * 16 + lr) * CH + t0);
            v8s o;
#pragma unroll
            for (int e = 0; e < 8; ++e) o[e] = (short)f2b(b2f((unsigned short)raw[e]) * w[e]);
            bf[j] = o;
        }
        v8s af[4];
#pragma unroll
        for (int i = 0; i < 4; ++i)
            af[i] = *(const v8s*)(Xr + (size_t)(i * 16 + lr) * CH + t0);
#pragma unroll
        for (int i = 0; i < 4; ++i)
#pragma unroll
            for (int j = 0; j < 2; ++j)
                acc[i][j] = __builtin_amdgcn_mfma_f32_16x16x32_bf16(af[i], bf[j], acc[i][j], 0, 0, 0);
    }
#pragma unroll
    for (int i = 0; i < 4; ++i)
#pragma unroll
        for (int j = 0; j < 2; ++j)
#pragma unroll
            for (int r = 0; r < 4; ++r)
                states[((size_t)(c * NH + h) * HD + i * 16 + quad * 4 + r) * DSTATE +
                       wave * 32 + j * 16 + lr] = acc[i][j][r];
}

// ---------------- sequential chunk scan, 512 blocks: prev_b[c] (bf16) = carry before chunk c
__global__ __launch_bounds__(256) void scan_kernel(const float* __restrict__ states,
                                                   const float* __restrict__ dAcs,
                                                   unsigned short* __restrict__ prev_b) {
    int h = blockIdx.x >> 3, seg = blockIdx.x & 7;
    int base = seg * 1024 + threadIdx.x * 4;
    float4 carry = {0.f, 0.f, 0.f, 0.f};
    for (int c = 0; c < NC; ++c) {
        size_t off = (size_t)(c * NH + h) * (HD * DSTATE) + base;
        ushort4 o = {f2b(carry.x), f2b(carry.y), f2b(carry.z), f2b(carry.w)};
        *(ushort4*)&prev_b[off] = o;
        float cd = __expf(dAcs[h * T_SEQ + c * CH + CH - 1]);
        float4 s = *(const float4*)&states[off];
        carry.x = fmaf(carry.x, cd, s.x);
        carry.y = fmaf(carry.y, cd, s.y);
        carry.z = fmaf(carry.z, cd, s.z);
        carry.w = fmaf(carry.w, cd, s.w);
    }
}

// ---------------- fused intra + inter chunk output, one block per (c,h)  [R4 version]
__global__ __launch_bounds__(256) void y12_mfma(const unsigned short* __restrict__ BCb,
                                                const unsigned short* __restrict__ Xt,
                                                const unsigned short* __restrict__ prev_b,
                                                const float* __restrict__ dt_s,
                                                const float* __restrict__ dAcs,
                                                const float* __restrict__ Dp,
                                                float* __restrict__ yacc) {
    __shared__ float s_da[CH], s_dt[CH];
    __shared__ unsigned short pw[4][16][40];
    const int h = blockIdx.x % NH, c = blockIdx.x / NH, g = h >> 3;
    const int tid = threadIdx.x, wave = tid >> 6, lane = tid & 63;
    const int lr = lane & 15, quad = lane >> 4;
    s_da[tid] = dAcs[h * T_SEQ + c * CH + tid];
    s_dt[tid] = dt_s[h * T_SEQ + c * CH + tid];
    __syncthreads();

    const unsigned short* Cb = BCb + (size_t)c * CH * BCW + NG * DSTATE + g * DSTATE;
    const unsigned short* Bb = BCb + (size_t)c * CH * BCW + g * DSTATE;
    const unsigned short* Xr = Xt + (size_t)(c * NH + h) * HD * CH;
    const unsigned short* Pr = prev_b + (size_t)(c * NH + h) * HD * DSTATE;
    const float Dh = Dp[h];

    v4f Y[4][4];  // [st_local][pj], st = i*4 + wave
#pragma unroll
    for (int i = 0; i < 4; ++i)
#pragma unroll
        for (int j = 0; j < 4; ++j) Y[i][j] = {0.f, 0.f, 0.f, 0.f};

    // ---- inter-chunk: Y += (e^{dA_s}·Cb) · prev^T
    {
        float es[4];
#pragma unroll
        for (int i = 0; i < 4; ++i) es[i] = __expf(s_da[(i * 4 + wave) * 16 + lr]);
#pragma unroll
        for (int kb = 0; kb < 4; ++kb) {
            const int n0 = kb * 32 + quad * 8;
            v8s bfp[4];
#pragma unroll
            for (int pj = 0; pj < 4; ++pj)
                bfp[pj] = *(const v8s*)(Pr + (size_t)(pj * 16 + lr) * DSTATE + n0);
#pragma unroll
            for (int i = 0; i < 4; ++i) {
                int st = i * 4 + wave;
                v8s raw = *(const v8s*)(Cb + (size_t)(st * 16 + lr) * BCW + n0);
                v8s af;
#pragma unroll
                for (int e = 0; e < 8; ++e) af[e] = (short)f2b(b2f((unsigned short)raw[e]) * es[i]);
#pragma unroll
                for (int pj = 0; pj < 4; ++pj)
                    Y[i][pj] = __builtin_amdgcn_mfma_f32_16x16x32_bf16(af, bfp[pj], Y[i][pj], 0, 0, 0);
            }
        }
    }

    // ---- intra-chunk (causal tiles only)
    for (int tb = 0; tb < 8; ++tb) {
        if (12 + wave < 2 * tb) continue;
        const int t0q = tb * 32 + quad * 8;
        v8s xf[4];
#pragma unroll
        for (int pj = 0; pj < 4; ++pj)
            xf[pj] = *(const v8s*)(Xr + (size_t)(pj * 16 + lr) * CH + t0q);
        v8s bfr[2][4];
#pragma unroll
        for (int j = 0; j < 2; ++j)
#pragma unroll
            for (int ks = 0; ks < 4; ++ks)
                bfr[j][ks] = *(const v8s*)(Bb + (size_t)(tb * 32 + j * 16 + lr) * BCW + ks * 32 + quad * 8);
#pragma unroll
        for (int i = 0; i < 4; ++i) {
            int st = i * 4 + wave;
            if (st < 2 * tb) continue;
            v4f S0 = {0.f, 0.f, 0.f, 0.f}, S1 = {0.f, 0.f, 0.f, 0.f};
#pragma unroll
            for (int ks = 0; ks < 4; ++ks) {
                v8s af = *(const v8s*)(Cb + (size_t)(st * 16 + lr) * BCW + ks * 32 + quad * 8);
                S0 = __builtin_amdgcn_mfma_f32_16x16x32_bf16(af, bfr[0][ks], S0, 0, 0, 0);
                S1 = __builtin_amdgcn_mfma_f32_16x16x32_bf16(af, bfr[1][ks], S1, 0, 0, 0);
            }
            int t0 = tb * 32 + lr;
            float da0 = s_da[t0], dt0 = s_dt[t0];
            float da1 = s_da[t0 + 16], dt1 = s_dt[t0 + 16];
#pragma unroll
            for (int r = 0; r < 4; ++r) {
                int s = st * 16 + quad * 4 + r;
                float das = s_da[s];
                float w0 = (t0 <= s) ? S0[r] * __expf(das - da0) * dt0 : 0.f;
                float w1 = (t0 + 16 <= s) ? S1[r] * __expf(das - da1) * dt1 : 0.f;
                if (t0 == s) w0 += Dh;            // D folded into diagonal
                if (t0 + 16 == s) w1 += Dh;
                pw[wave][quad * 4 + r][lr] = f2b(w0);
                pw[wave][quad * 4 + r][16 + lr] = f2b(w1);
            }
            v8s pf = *(const v8s*)(&pw[wave][lr][quad * 8]);  // same-wave LDS round-trip
#pragma unroll
            for (int pj = 0; pj < 4; ++pj)
                Y[i][pj] = __builtin_amdgcn_mfma_f32_16x16x32_bf16(pf, xf[pj], Y[i][pj], 0, 0, 0);
        }
    }
    // epilogue: single write
#pragma unroll
    for (int i = 0; i < 4; ++i) {
        int st = i * 4 + wave;
#pragma unroll
        for (int pj = 0; pj < 4; ++pj) {
            int p = pj * 16 + lr;
#pragma unroll
            for (int r = 0; r < 4; ++r) {
                int s = st * 16 + quad * 4 + r;
                yacc[(size_t)(c * CH + s) * DIN + h * HD + p] = Y[i][pj][r];
            }
        }
    }
}

// ---------------- fused: grouped RMSNorm+gate (blocks 0..8191, 2 groups/block)
//                  and out_proj_w fp32->bf16 convert (blocks 8192..16383)
__global__ __launch_bounds__(256) void normcvt_kernel(const unsigned short* __restrict__ zxb,
                                                      const float* __restrict__ yacc,
                                                      const float* __restrict__ norm_w,
                                                      unsigned short* __restrict__ ynorm,
                                                      const float4* __restrict__ osrc,
                                                      ushort4* __restrict__ odst) {
    if (blockIdx.x < 8192) {
        __shared__ float red[4];
        const int sub = threadIdx.x >> 7, tid = threadIdx.x & 127;
        const int gid = blockIdx.x * 2 + sub;
        const int t = gid / NG, g = gid % NG;
        const int j = g * 512 + tid * 4;
        float4 y4 = *(const float4*)&yacc[(size_t)t * DIN + j];
        ushort4 z4 = *(const ushort4*)&zxb[(size_t)t * DPROJP + j];
        float v0 = y4.x * silu_f(b2f(z4.x));
        float v1 = y4.y * silu_f(b2f(z4.y));
        float v2 = y4.z * silu_f(b2f(z4.z));
        float v3 = y4.w * silu_f(b2f(z4.w));
        float ss = v0 * v0 + v1 * v1 + v2 * v2 + v3 * v3;
#pragma unroll
        for (int off = 32; off > 0; off >>= 1) ss += __shfl_down(ss, off, 64);
        if ((threadIdx.x & 63) == 0) red[threadIdx.x >> 6] = ss;
        __syncthreads();
        float var = (red[sub * 2] + red[sub * 2 + 1]) * (1.0f / 512.0f);
        float scale = rsqrtf(var + EPS);
        float4 w4 = *(const float4*)&norm_w[j];
        ushort4 o = {f2b(v0 * scale * w4.x), f2b(v1 * scale * w4.y),
                     f2b(v2 * scale * w4.z), f2b(v3 * scale * w4.w)};
        *(ushort4*)&ynorm[(size_t)t * DIN + j] = o;
    } else {
        int i = (blockIdx.x - 8192) * 256 + threadIdx.x;   // i < DMODEL*DIN/4 = 2,097,152
        float4 v = osrc[i];
        ushort4 o = {f2b(v.x), f2b(v.y), f2b(v.z), f2b(v.w)};
        odst[i] = o;
    }
}

extern "C" void kernel_launch(void* const* d_in, const int* in_sizes, int n_in,
                              void* d_out, int out_size, void* d_ws, size_t ws_size,
                              hipStream_t stream) {
    const float* hidden     = (const float*)d_in[0];
    const float* in_proj_w  = (const float*)d_in[1];
    const float* conv_w     = (const float*)d_in[2];
    const float* conv_b     = (const float*)d_in[3];
    const float* A          = (const float*)d_in[4];
    const float* Dp         = (const float*)d_in[5];
    const float* dt_bias    = (const float*)d_in[6];
    const float* norm_w     = (const float*)d_in[7];
    const float* out_proj_w = (const float*)d_in[8];
    float* out = (float*)d_out;

    // workspace layout (fp32 words) — total 34,209,792 words = 136.8 MB
    float* ws     = (float*)d_ws;
    unsigned short* zxb = (unsigned short*)ws;          // bf16 [T, DPROJP]: 10,616,832 w
    float* dt_raw = ws + 10616832;                      //                     131,072 w
    float* dt_s   = dt_raw + 131072;                    //                     131,072 w
    float* dAcs   = dt_s + 131072;                      //                     131,072 w
    float* yacc   = dAcs + 131072;                      // fp32 [T, DIN]:    8,388,608 w
    float* regE   = yacc + 8388608;                     //                  10,616,832 w
    float* regF   = regE + 10616832;                    //                   4,194,304 w

    // regE phases: inw_b (gemm1, 42.5MB) -> Xt [0,4.19M w) + states [4.19M,8.39M w)
    //              -> outw_b [0,4.19M w) after y12
    unsigned short* inw_b  = (unsigned short*)regE;
    unsigned short* Xt_b   = (unsigned short*)regE;                 // conv -> y12
    float*          states = regE + 4194304;                        // states_mfma -> scan
    unsigned short* outw_b = (unsigned short*)regE;                 // cvt -> out-proj
    // regF phases: hidden_b (gemm1) -> BCb [0,2.1M w) + Btr [2.1M,3.15M w)
    //              -> prev_b [2.1M,4.19M w) over Btr after states -> ynorm_b [0,4.19M w) after y12
    unsigned short* hidden_b = (unsigned short*)regF;
    unsigned short* BCb      = (unsigned short*)regF;
    unsigned short* Btr      = (unsigned short*)(regF + 2097152);
    unsigned short* prev_b   = (unsigned short*)(regF + 2097152);
    unsigned short* ynorm_b  = (unsigned short*)regF;

    // --- fused front converts (in_proj_w + hidden)
    {
        int n4s = DPROJ * DMODEL / 4, n4d = DPROJP * DMODEL / 4;
        int h4 = T_SEQ * DMODEL / 4;
        cvt_front<<<(n4d + h4 + 255) / 256, 256, 0, stream>>>(
            (const float4*)in_proj_w, (ushort4*)inw_b, n4s, n4d,
            (const float4*)hidden, (ushort4*)hidden_b, h4);
    }
    // --- in-proj GEMM: 1-D grid 1296 (16 m x 81 n), XCD-chunked swizzle m-fast
    gemm_bf16<128, true><<<dim3(16 * 81), 256, 0, stream>>>(
        hidden_b, inw_b, nullptr, zxb, dt_raw, T_SEQ, DPROJP, DMODEL, 0, 16);

    // --- fused conv + dt (1280 blocks)
    convdt_kernel<<<NC * 96 + NC * NH, 256, 0, stream>>>(
        zxb, conv_w, conv_b, Xt_b, BCb, Btr, dt_raw, A, dt_bias, dt_s, dAcs);

    states_mfma<<<NC * NH, 256, 0, stream>>>(Xt_b, Btr, dt_s, dAcs, states);
    scan_kernel<<<NH * 8, 256, 0, stream>>>(states, dAcs, prev_b);
    y12_mfma<<<NC * NH, 256, 0, stream>>>(BCb, Xt_b, prev_b, dt_s, dAcs, Dp, yacc);

    // --- fused norm (2 groups/block) + out_proj_w convert (Xt + states dead now)
    normcvt_kernel<<<16384, 256, 0, stream>>>(
        zxb, yacc, norm_w, ynorm_b, (const float4*)out_proj_w, (ushort4*)outw_b);

    // --- out-proj GEMM: R4 config — gemm64 BN=64/BK=64, 2-D grid (16,32), no swizzle
    gemm64_bf16<64, false><<<dim3(16, 32), 256, 0, stream>>>(
        ynorm_b, outw_b, out, nullptr, nullptr, T_SEQ, DMODEL, DIN, 0);
}